// Round 1
// baseline (103.619 us; speedup 1.0000x reference)
//
#include <hip/hip_runtime.h>
#include <math.h>

// ---------------------------------------------------------------------------
// MILossGaussian via MFMA: hist_joint(64x64) = Wx(64,P) . Wy^T(P,64) per n.
//
// R3: kill the 2x LDS read amplification of the quadrant decomposition.
// Each WAVE now owns a private K-slice: per 64-column chunk it writes its own
// A/B tiles (one column per lane), then computes the FULL 64x64 C by loading
// a0/a1/b0/b1 fragments once per k-step and issuing all 4 quadrant MFMAs from
// registers (read amp 2.0 -> 1.0: 16 ds_read_b128 + 16 MFMA per chunk).
// Tiles are wave-private and columns lane-private -> NO __syncthreads in the
// main loop (DS ops from one wave are processed in order; compiler emits the
// lgkmcnt for the may-aliasing write->read). Global x/y loads are prefetched
// one chunk ahead to hide HBM latency under exp+MFMA.
// Block = 128 threads (2 waves) so static LDS = 36864 B < 64 KiB;
// grid = 1024 blocks = 4 blocks/CU (LDS 147 KB/CU), 8 waves/CU as before.
// Cross-wave reduce in LDS before global atomicAdd (4096 atomics/block).
//
// Weight math identical to the verified R2 kernel (absmax 0.0):
// sigma = (1/64)/2.3548 -> w = exp(-2.86131*d^2) in bin-step units; 5-bin
// window (RAD=2), center clamped to [2,61] with delta from true position;
// kCoef dropped (p_joint scale-invariant); C vs C^T harmless (x<->y symmetry).
// ---------------------------------------------------------------------------

#define NBINS 64
#define LDA2 72                 // halfs per row: 144 B = 9*16B -> b128-aligned rows,
                                // row quad-bank stride 9 mod 8 = 1 -> balanced banks
#define TILEH (NBINS * LDA2)    // 4608 halfs = 9216 B per tile

typedef _Float16 half8    __attribute__((ext_vector_type(8)));
typedef float    floatx16 __attribute__((ext_vector_type(16)));

static constexpr double kSigmaD = 0.015625 / 2.3548200450309493;  // BIN_WIDTH/(2*sqrt(2*ln2))
static constexpr double kAcD    = (1.0 / (63.0 * 63.0)) / (2.0 * kSigmaD * kSigmaD);
static constexpr float  kAc     = (float)kAcD;                    // 2.86131
static constexpr float  kEps    = 1e-10f;

// zero the 2*64*64 global hist AND the output scalar (harness poisons both)
__global__ void zero_ws_kernel(float* __restrict__ hist, float* __restrict__ out, int n) {
    int i = blockIdx.x * blockDim.x + threadIdx.x;
    if (i < n) hist[i] = 0.0f;
    if (i == 0) out[0] = 0.0f;
}

__global__ __launch_bounds__(128, 2) void hist_gemm_kernel(
        const float* __restrict__ x, const float* __restrict__ y,
        float* __restrict__ hist, int P, int elemsPerWave) {
    // per-wave private tiles: [wave][A=0/B=1][row][k]
    __shared__ __align__(16) _Float16 tiles[2][2][NBINS][LDA2];   // 36864 B

    const int t    = threadIdx.x;
    const int lane = t & 63;
    const int wave = t >> 6;
    const int n    = blockIdx.y;

    _Float16* __restrict__ Ax = &tiles[wave][0][0][0];
    _Float16* __restrict__ By = &tiles[wave][1][0][0];

    // zero this wave's own tiles (barrier-free: wave-private)
    {
        float4* p4 = (float4*)Ax;                      // Ax,By contiguous: 18432 B
        const int n16 = 2 * TILEH * 2 / 16;            // 1152 float4
        for (int i = lane; i < n16; i += 64) p4[i] = float4{0.f, 0.f, 0.f, 0.f};
    }

    floatx16 acc[2][2] = {};                           // full 64x64 C per wave
    const float* __restrict__ xp = x + (size_t)n * P;
    const float* __restrict__ yp = y + (size_t)n * P;

    const int waveBase = (blockIdx.x * 2 + wave) * elemsPerWave;
    int lim = P - waveBase;                            // robustness vs exact split
    if (lim > elemsPerWave) lim = elemsPerWave;
    const int nChunks = (elemsPerWave + 63) / 64;      // 14 (last chunk half-masked)

#define GLOAD(c2, ox, oy) do {                                   \
        int off_ = (c2) * 64 + lane;                             \
        int g_ = waveBase + ((off_ < lim) ? off_ : 0);           \
        g_ = min(g_, P - 1);                                     \
        ox = xp[g_]; oy = yp[g_];                                \
    } while (0)

    int pcx = 2, pcy = 2;                              // previous stamp centers (rows 0..4 start zero)
    float vx, vy;
    GLOAD(0, vx, vy);                                  // prefetch chunk 0

    for (int c = 0; c < nChunks; ++c) {
        // prefetch next chunk's element while we crunch this one
        float nvx = 0.f, nvy = 0.f;
        if (c + 1 < nChunks) GLOAD(c + 1, nvx, nvy);

        const bool valid = (c * 64 + lane) < lim;
        float wx[5], wy[5];
        int cx = 2, cy = 2;
        if (valid) {
            const float sx = vx * 63.0f;
            const float sy = vy * 63.0f;
            cx = min(max((int)(sx + 0.5f), 2), 61);
            cy = min(max((int)(sy + 0.5f), 2), 61);
            const float dx = sx - (float)cx;
            const float dy = sy - (float)cy;
#pragma unroll
            for (int k = 0; k < 5; ++k) {
                const float ddx = dx - (float)(k - 2);
                const float ddy = dy - (float)(k - 2);
                wx[k] = __expf(-kAc * ddx * ddx);
                wy[k] = __expf(-kAc * ddy * ddy);
            }
        } else {
#pragma unroll
            for (int k = 0; k < 5; ++k) { wx[k] = 0.0f; wy[k] = 0.0f; }
        }

        // un-write previous stamp, then write new one (lane owns column `lane`)
#pragma unroll
        for (int k = 0; k < 5; ++k) {
            Ax[(pcx - 2 + k) * LDA2 + lane] = (_Float16)0.0f;
            By[(pcy - 2 + k) * LDA2 + lane] = (_Float16)0.0f;
        }
#pragma unroll
        for (int k = 0; k < 5; ++k) {
            Ax[(cx - 2 + k) * LDA2 + lane] = (_Float16)wx[k];
            By[(cy - 2 + k) * LDA2 + lane] = (_Float16)wy[k];
        }
        pcx = cx; pcy = cy;

        // fragments: A[m=lane&31][k = kb*16 + 8*(lane>>5) + j]; amp 1.0:
        // each 16B row segment read exactly once, all 4 quadrants from regs.
        const int mrow = lane & 31;
        const int kq   = 8 * (lane >> 5);
        const _Float16* pa = &Ax[mrow * LDA2 + kq];
        const _Float16* pb = &By[mrow * LDA2 + kq];
#pragma unroll
        for (int kb = 0; kb < 4; ++kb) {
            const half8 a0 = *(const half8*)(pa + kb * 16);
            const half8 a1 = *(const half8*)(pa + 32 * LDA2 + kb * 16);
            const half8 b0 = *(const half8*)(pb + kb * 16);
            const half8 b1 = *(const half8*)(pb + 32 * LDA2 + kb * 16);
            acc[0][0] = __builtin_amdgcn_mfma_f32_32x32x16_f16(a0, b0, acc[0][0], 0, 0, 0);
            acc[0][1] = __builtin_amdgcn_mfma_f32_32x32x16_f16(a0, b1, acc[0][1], 0, 0, 0);
            acc[1][0] = __builtin_amdgcn_mfma_f32_32x32x16_f16(a1, b0, acc[1][0], 0, 0, 0);
            acc[1][1] = __builtin_amdgcn_mfma_f32_32x32x16_f16(a1, b1, acc[1][1], 0, 0, 0);
        }

        vx = nvx; vy = nvy;
    }
#undef GLOAD

    // epilogue: C/D layout col=lane&31, row=(r&3)+8*(r>>2)+4*(lane>>5).
    // Dump each wave's 64x64 into its own tile region (16384 B of 18432),
    // reduce across the 2 waves, one atomicAdd per address per block.
    float* wsum = (float*)&tiles[wave][0][0][0];
#pragma unroll
    for (int qi = 0; qi < 2; ++qi)
#pragma unroll
        for (int qj = 0; qj < 2; ++qj)
#pragma unroll
            for (int r = 0; r < 16; ++r) {
                const int row = qi * 32 + (r & 3) + 8 * (r >> 2) + 4 * (lane >> 5);
                const int col = qj * 32 + (lane & 31);
                wsum[row * NBINS + col] = acc[qi][qj][r];
            }
    __syncthreads();

    float* __restrict__ gh = hist + (size_t)n * NBINS * NBINS;
    const float* w0 = (const float*)&tiles[0][0][0][0];
    const float* w1 = (const float*)&tiles[1][0][0][0];
    for (int i = t; i < NBINS * NBINS; i += 128) {
        atomicAdd(&gh[i], w0[i] + w1[i]);
    }
}

__device__ __forceinline__ float block_sum_bcast(float v, float* sm) {
#pragma unroll
    for (int off = 32; off > 0; off >>= 1) v += __shfl_down(v, off, 64);
    __syncthreads();
    const int lane = threadIdx.x & 63;
    const int wid  = threadIdx.x >> 6;
    if (lane == 0) sm[wid] = v;
    __syncthreads();
    return sm[0] + sm[1] + sm[2] + sm[3];
}

// grid = 2 blocks (one per n); each atomically adds -0.5*ratio into out[0].
__global__ __launch_bounds__(256) void finalize_kernel(
        const float* __restrict__ hist, float* __restrict__ out) {
    __shared__ float sm[4];
    __shared__ float sx[NBINS];
    __shared__ float sy[NBINS];

    const int n = blockIdx.x;
    const float* __restrict__ h = hist + (size_t)n * NBINS * NBINS;

    float s = 0.0f;
    for (int i = threadIdx.x; i < NBINS * NBINS; i += 256) s += h[i];
    const float S = block_sum_bcast(s, sm) + kEps;
    const float invS = 1.0f / S;

    float ej = 0.0f;
    for (int i = threadIdx.x; i < NBINS * NBINS; i += 256) {
        const float p = h[i] * invS;
        ej += p * __logf(p + kEps);
    }

    if (threadIdx.x < NBINS) {
        float px = 0.0f;
        const float* rp = &h[threadIdx.x * NBINS];
        for (int c = 0; c < NBINS; c++) px += rp[c];
        px *= invS;
        sx[threadIdx.x] = px * __logf(px + kEps);
    } else if (threadIdx.x < 2 * NBINS) {
        const int c = threadIdx.x - NBINS;
        float py = 0.0f;
        for (int b = 0; b < NBINS; b++) py += h[b * NBINS + c];
        py *= invS;
        sy[c] = py * __logf(py + kEps);
    }

    const float EJ = block_sum_bcast(ej, sm);
    const float mx = (threadIdx.x < NBINS) ? sx[threadIdx.x] : 0.0f;
    const float my = (threadIdx.x < NBINS) ? sy[threadIdx.x] : 0.0f;
    const float EX = block_sum_bcast(mx, sm);
    const float EY = block_sum_bcast(my, sm);

    if (threadIdx.x == 0) atomicAdd(out, -0.5f * ((EX + EY) / EJ));
}

extern "C" void kernel_launch(void* const* d_in, const int* in_sizes, int n_in,
                              void* d_out, int out_size, void* d_ws, size_t ws_size,
                              hipStream_t stream) {
    const float* x = (const float*)d_in[0];
    const float* y = (const float*)d_in[1];
    float* hist = (float*)d_ws;            // 2 * 64 * 64 floats = 32 KB
    float* out  = (float*)d_out;

    const int N = 2;
    const int P = in_sizes[0] / N;                 // 884736
    const int blocksPerN   = 512;                  // 1024 blocks total -> 4/CU (36.9 KB LDS each)
    const int elemsPerWave = P / (blocksPerN * 2); // 864 (exact)

    const int histElems = N * NBINS * NBINS;
    zero_ws_kernel<<<(histElems + 255) / 256, 256, 0, stream>>>(hist, out, histElems);

    dim3 grid(blocksPerN, N);
    hist_gemm_kernel<<<grid, 128, 0, stream>>>(x, y, hist, P, elemsPerWave);

    finalize_kernel<<<2, 256, 0, stream>>>(hist, out);
}